// Round 9
// baseline (1689.009 us; speedup 1.0000x reference)
//
#include <hip/hip_runtime.h>

#define NN 10000
#define EE 320000
#define ET (EE + NN)      // 330000 edges incl self-loops
#define FIN 256
#define HD 128
#define NEG 0.2f
#define NB 1024           // == 256 CUs x 4 blocks/CU (guaranteed by launch_bounds)
#define NT 256
#define GT (NB * NT)

// Inputs fp32, edge_index int32, OUTPUT fp32.

struct GatP {
    const float* x; const int* ei;
    const float* W1; const float* as1; const float* ad1; const float* b1;
    const float* W2; const float* as2; const float* ad2; const float* b2;
    const float* Wr; const float* br; const float* Wc; const float* bc;
    float* out;
    float* h; float* g1; float* a_s; float* a_d;
    int* counts; int* offsets; int* cursor; int* srclist; int* bar;
};

// device-scope grid barrier: monotonic counter, never reset (no reuse race).
// Release fetch_add writes back the XCD L2; acquire load invalidates -> phase
// k's plain stores are visible to phase k+1 on every XCD. Bounded spin turns a
// (theoretically impossible) non-residency deadlock into a clean wrong answer.
__device__ __forceinline__ void gbar(int* bar, int tgt) {
    __syncthreads();
    if (threadIdx.x == 0) {
        __threadfence();
        __hip_atomic_fetch_add(bar, 1, __ATOMIC_RELEASE, __HIP_MEMORY_SCOPE_AGENT);
        int spins = 0;
        while (__hip_atomic_load(bar, __ATOMIC_ACQUIRE, __HIP_MEMORY_SCOPE_AGENT) < tgt) {
            __builtin_amdgcn_s_sleep(2);
            if (++spins > 5000000) break;   // safety valve
        }
    }
    __syncthreads();
}

__device__ __forceinline__ float edge_w(float as_v, float adn) {
    float e = as_v + adn;
    e = (e > 0.f) ? e : NEG * e;
    return __expf(e);
}

__global__ __launch_bounds__(NT, 4) void k_fused(GatP p) {
    __shared__ float xs[8192];   // 32 KB, reused per phase
    const int t = threadIdx.x;
    const int b = blockIdx.x;
    const int gtid = b * NT + t;

    // ---- P0: zero counts; seed out with bc (out pre-zeroed by memset node) ----
    for (int i = gtid; i < NN; i += GT) p.counts[i] = 0;
    if (gtid == 0) {
        atomicAdd(&p.out[0], p.bc[0]);
        atomicAdd(&p.out[1], p.bc[1]);
    }
    gbar(p.bar, 1 * NB);

    // ---- P1: histogram of dst ----
    for (int i = gtid; i < ET; i += GT) {
        int d = (i < EE) ? p.ei[EE + i] : (i - EE);
        atomicAdd(&p.counts[d], 1);
    }
    gbar(p.bar, 2 * NB);

    // ---- P2: full exclusive scan in block 0 (counts -> offsets, cursor) ----
    if (b == 0) {
        const int CHUNK = 40;   // 256*40 = 10240 >= 10000
        int* sm = (int*)xs;
        int base = t * CHUNK;
        int s = 0;
        for (int i = 0; i < CHUNK; i++) {
            int idx = base + i;
            if (idx < NN) s += p.counts[idx];
        }
        sm[t] = s;
        __syncthreads();
        for (int off = 1; off < NT; off <<= 1) {
            int v = (t >= off) ? sm[t - off] : 0;
            __syncthreads();
            sm[t] += v;
            __syncthreads();
        }
        int run = (t > 0) ? sm[t - 1] : 0;
        for (int i = 0; i < CHUNK; i++) {
            int idx = base + i;
            if (idx < NN) {
                p.offsets[idx] = run;
                p.cursor[idx]  = run;
                run += p.counts[idx];
            }
        }
        if (t == NT - 1) p.offsets[NN] = sm[NT - 1];
    }
    gbar(p.bar, 3 * NB);

    // ---- P3: scatter source ids into CSR ----
    for (int i = gtid; i < ET; i += GT) {
        int s, d;
        if (i < EE) { s = p.ei[i]; d = p.ei[EE + i]; }
        else        { s = i - EE; d = s; }
        int pos = atomicAdd(&p.cursor[d], 1);
        p.srclist[pos] = s;
    }
    gbar(p.bar, 4 * NB);

    // ---- P4: gemm1  h = x@W1, a_s, a_d (wave-group = 8 nodes, LDS-staged x) ----
    {
        int g4 = t >> 6, tt = t & 63, f = tt * 2;
        int ng = b + NB * g4;                      // slots 0..4095, work 0..1249
        bool act = ng < (NN / 8);
        if (act) {
            float4* xw4 = (float4*)(xs + g4 * 2048);
            const float4* xv = (const float4*)(p.x + (size_t)ng * 8 * FIN);
            #pragma unroll
            for (int i2 = 0; i2 < 8; i2++) xw4[tt + 64 * i2] = xv[tt + 64 * i2];
        }
        __syncthreads();
        if (act) {
            const float* xw = xs + g4 * 2048;
            float2 acc[8];
            #pragma unroll
            for (int m = 0; m < 8; m++) acc[m] = make_float2(0.f, 0.f);
            for (int k = 0; k < FIN; k += 4) {
                float2 w0 = *(const float2*)&p.W1[(k + 0) * HD + f];
                float2 w1 = *(const float2*)&p.W1[(k + 1) * HD + f];
                float2 w2 = *(const float2*)&p.W1[(k + 2) * HD + f];
                float2 w3 = *(const float2*)&p.W1[(k + 3) * HD + f];
                #pragma unroll
                for (int m = 0; m < 8; m++) {
                    float4 xk = *(const float4*)&xw[m * FIN + k];
                    acc[m].x += xk.x * w0.x; acc[m].y += xk.x * w0.y;
                    acc[m].x += xk.y * w1.x; acc[m].y += xk.y * w1.y;
                    acc[m].x += xk.z * w2.x; acc[m].y += xk.z * w2.y;
                    acc[m].x += xk.w * w3.x; acc[m].y += xk.w * w3.y;
                }
            }
            float2 ats = *(const float2*)&p.as1[f];
            float2 atd = *(const float2*)&p.ad1[f];
            #pragma unroll
            for (int m = 0; m < 8; m++) {
                int node = ng * 8 + m;
                *(float2*)&p.h[(size_t)node * HD + f] = acc[m];
                float vs = acc[m].x * ats.x + acc[m].y * ats.y;
                float vd = acc[m].x * atd.x + acc[m].y * atd.y;
                #pragma unroll
                for (int off = 32; off > 0; off >>= 1) {
                    vs += __shfl_down(vs, off);
                    vd += __shfl_down(vd, off);
                }
                if (tt == 0) { p.a_s[node] = vs; p.a_d[node] = vd; }
            }
        }
    }
    gbar(p.bar, 5 * NB);

    // ---- P5: agg1 (wave per node, 4-deep unroll) -> g1 = relu(agg + b1) ----
    {
        int w = (b << 2) + (t >> 6), l = t & 63;
        const float2* h2 = (const float2*)p.h;
        for (int node = w; node < NN; node += NB * 4) {
            int beg = p.offsets[node], end = p.offsets[node + 1];
            float adn = p.a_d[node];
            float ax = 0.f, ay = 0.f, z = 0.f;
            int pp = beg;
            for (; pp + 4 <= end; pp += 4) {
                int s0 = p.srclist[pp],     s1 = p.srclist[pp + 1];
                int s2 = p.srclist[pp + 2], s3 = p.srclist[pp + 3];
                float2 h0 = h2[(size_t)s0 * 64 + l];
                float2 h1 = h2[(size_t)s1 * 64 + l];
                float2 hh = h2[(size_t)s2 * 64 + l];
                float2 h3 = h2[(size_t)s3 * 64 + l];
                float w0 = edge_w(p.a_s[s0], adn);
                float w1 = edge_w(p.a_s[s1], adn);
                float w2 = edge_w(p.a_s[s2], adn);
                float w3 = edge_w(p.a_s[s3], adn);
                z += (w0 + w1) + (w2 + w3);
                ax += w0 * h0.x + w1 * h1.x + w2 * hh.x + w3 * h3.x;
                ay += w0 * h0.y + w1 * h1.y + w2 * hh.y + w3 * h3.y;
            }
            for (; pp < end; pp++) {
                int s = p.srclist[pp];
                float2 hv = h2[(size_t)s * 64 + l];
                float ww = edge_w(p.a_s[s], adn);
                z += ww;
                ax += ww * hv.x;
                ay += ww * hv.y;
            }
            float2 bb = *(const float2*)&p.b1[2 * l];
            float ox = ax / z + bb.x, oy = ay / z + bb.y;
            ox = (ox > 0.f) ? ox : 0.f;
            oy = (oy > 0.f) ? oy : 0.f;
            *(float2*)&p.g1[(size_t)node * HD + 2 * l] = make_float2(ox, oy);
        }
    }
    gbar(p.bar, 6 * NB);

    // ---- P6: gemm2  h = g1@W2, a_s, a_d ----
    {
        int g4 = t >> 6, tt = t & 63, f = tt * 2;
        int ng = b + NB * g4;
        bool act = ng < (NN / 8);
        if (act) {
            float4* xw4 = (float4*)(xs + g4 * 2048);
            const float4* xv = (const float4*)(p.g1 + (size_t)ng * 8 * HD);
            #pragma unroll
            for (int i2 = 0; i2 < 4; i2++) xw4[tt + 64 * i2] = xv[tt + 64 * i2];
        }
        __syncthreads();
        if (act) {
            const float* xw = xs + g4 * 2048;
            float2 acc[8];
            #pragma unroll
            for (int m = 0; m < 8; m++) acc[m] = make_float2(0.f, 0.f);
            for (int k = 0; k < HD; k += 4) {
                float2 w0 = *(const float2*)&p.W2[(k + 0) * HD + f];
                float2 w1 = *(const float2*)&p.W2[(k + 1) * HD + f];
                float2 w2 = *(const float2*)&p.W2[(k + 2) * HD + f];
                float2 w3 = *(const float2*)&p.W2[(k + 3) * HD + f];
                #pragma unroll
                for (int m = 0; m < 8; m++) {
                    float4 xk = *(const float4*)&xw[m * HD + k];
                    acc[m].x += xk.x * w0.x; acc[m].y += xk.x * w0.y;
                    acc[m].x += xk.y * w1.x; acc[m].y += xk.y * w1.y;
                    acc[m].x += xk.z * w2.x; acc[m].y += xk.z * w2.y;
                    acc[m].x += xk.w * w3.x; acc[m].y += xk.w * w3.y;
                }
            }
            float2 ats = *(const float2*)&p.as2[f];
            float2 atd = *(const float2*)&p.ad2[f];
            #pragma unroll
            for (int m = 0; m < 8; m++) {
                int node = ng * 8 + m;
                *(float2*)&p.h[(size_t)node * HD + f] = acc[m];
                float vs = acc[m].x * ats.x + acc[m].y * ats.y;
                float vd = acc[m].x * atd.x + acc[m].y * atd.y;
                #pragma unroll
                for (int off = 32; off > 0; off >>= 1) {
                    vs += __shfl_down(vs, off);
                    vd += __shfl_down(vd, off);
                }
                if (tt == 0) { p.a_s[node] = vs; p.a_d[node] = vd; }
            }
        }
    }
    gbar(p.bar, 7 * NB);

    // ---- P7: agg2 + reduce_dim + classifier partials -> 2 atomics per block ----
    {
        int wv = t >> 6, l = t & 63;
        int w = (b << 2) + wv;
        const float2* h2 = (const float2*)p.h;
        float br0 = p.br[0];
        float c0 = 0.f, c1 = 0.f;            // lane-0-only classifier partials
        for (int node = w; node < NN; node += NB * 4) {
            int beg = p.offsets[node], end = p.offsets[node + 1];
            float adn = p.a_d[node];
            float ax = 0.f, ay = 0.f, z = 0.f;
            int pp = beg;
            for (; pp + 4 <= end; pp += 4) {
                int s0 = p.srclist[pp],     s1 = p.srclist[pp + 1];
                int s2 = p.srclist[pp + 2], s3 = p.srclist[pp + 3];
                float2 h0 = h2[(size_t)s0 * 64 + l];
                float2 h1 = h2[(size_t)s1 * 64 + l];
                float2 hh = h2[(size_t)s2 * 64 + l];
                float2 h3 = h2[(size_t)s3 * 64 + l];
                float w0 = edge_w(p.a_s[s0], adn);
                float w1 = edge_w(p.a_s[s1], adn);
                float w2 = edge_w(p.a_s[s2], adn);
                float w3 = edge_w(p.a_s[s3], adn);
                z += (w0 + w1) + (w2 + w3);
                ax += w0 * h0.x + w1 * h1.x + w2 * hh.x + w3 * h3.x;
                ay += w0 * h0.y + w1 * h1.y + w2 * hh.y + w3 * h3.y;
            }
            for (; pp < end; pp++) {
                int s = p.srclist[pp];
                float2 hv = h2[(size_t)s * 64 + l];
                float ww = edge_w(p.a_s[s], adn);
                z += ww;
                ax += ww * hv.x;
                ay += ww * hv.y;
            }
            float2 bb = *(const float2*)&p.b2[2 * l];
            float ox = ax / z + bb.x, oy = ay / z + bb.y;
            ox = (ox > 0.f) ? ox : 0.f;
            oy = (oy > 0.f) ? oy : 0.f;
            float2 wr = *(const float2*)&p.Wr[2 * l];
            float part = ox * wr.x + oy * wr.y;
            #pragma unroll
            for (int off = 32; off > 0; off >>= 1) part += __shfl_down(part, off);
            if (l == 0) {
                float rv = part + br0;
                c0 += rv * p.Wc[2 * node];
                c1 += rv * p.Wc[2 * node + 1];
            }
        }
        __syncthreads();                      // xs reuse safe (P6 done in-block)
        float* cred = xs;
        if (l == 0) { cred[wv] = c0; cred[4 + wv] = c1; }
        __syncthreads();
        if (t == 0) {
            atomicAdd(&p.out[0], cred[0] + cred[1] + cred[2] + cred[3]);
            atomicAdd(&p.out[1], cred[4] + cred[5] + cred[6] + cred[7]);
        }
    }
}

// ---------------- launch ----------------

extern "C" void kernel_launch(void* const* d_in, const int* in_sizes, int n_in,
                              void* d_out, int out_size, void* d_ws, size_t ws_size,
                              hipStream_t stream) {
    GatP p;
    p.x   = (const float*)d_in[0];
    p.ei  = (const int*)d_in[1];
    p.W1  = (const float*)d_in[2];
    p.as1 = (const float*)d_in[3];
    p.ad1 = (const float*)d_in[4];
    p.b1  = (const float*)d_in[5];
    p.W2  = (const float*)d_in[6];
    p.as2 = (const float*)d_in[7];
    p.ad2 = (const float*)d_in[8];
    p.b2  = (const float*)d_in[9];
    p.Wr  = (const float*)d_in[10];
    p.br  = (const float*)d_in[11];
    p.Wc  = (const float*)d_in[12];
    p.bc  = (const float*)d_in[13];
    p.out = (float*)d_out;

    float* f = (float*)d_ws;
    p.h   = f;                      f += (size_t)NN * HD;
    p.g1  = f;                      f += (size_t)NN * HD;
    p.a_s = f;                      f += NN;
    p.a_d = f;                      f += NN;
    int* ip = (int*)f;
    p.counts  = ip;                 ip += NN;
    p.offsets = ip;                 ip += NN + 1;
    p.cursor  = ip;                 ip += NN;
    p.srclist = ip;                 ip += ET;
    p.bar     = ip;                 ip += 4;

    hipMemsetAsync(p.bar, 0, 4 * sizeof(int), stream);
    hipMemsetAsync(p.out, 0, 2 * sizeof(float), stream);
    k_fused<<<NB, NT, 0, stream>>>(p);
}

// Round 10
// 641.027 us; speedup vs baseline: 2.6348x; 2.6348x over previous
//
#include <hip/hip_runtime.h>

#define NN 10000
#define EE 320000
#define ET (EE + NN)      // 330000 edges incl self-loops
#define FIN 256
#define HD 128
#define NEG 0.2f
#define NB 1024           // == 256 CUs x 4 blocks/CU (co-resident by launch_bounds)
#define NT 256
#define GT (NB * NT)

// Inputs fp32, edge_index int32, OUTPUT fp32.

struct GatP {
    const float* x; const int* ei;
    const float* W1; const float* as1; const float* ad1; const float* b1;
    const float* W2; const float* as2; const float* ad2; const float* b2;
    const float* Wr; const float* br; const float* Wc; const float* bc;
    float* out;
    float* h; float* g1; float* a_s; float* a_d;
    int* counts; int* bar; int* offsets; int* cursor; int* srclist;
};

// Grid barrier, monotonic counter. Arrival: agent-RELEASE fetch_add (one wbl2 —
// flushes this XCD's L2, covering all blockmates' prior stores since
// __syncthreads drained vmcnt). Poll: RELAXED agent loads (NO buffer_inv per
// poll — round 9's 7x regression was acquire-per-poll invalidate storms), then
// a single acquire fence on exit. Bounded spin = safety valve.
__device__ __forceinline__ void gbar(int* bar, int tgt) {
    __syncthreads();
    if (threadIdx.x == 0) {
        __hip_atomic_fetch_add(bar, 1, __ATOMIC_RELEASE, __HIP_MEMORY_SCOPE_AGENT);
        int spins = 0;
        while (__hip_atomic_load(bar, __ATOMIC_RELAXED, __HIP_MEMORY_SCOPE_AGENT) < tgt) {
            __builtin_amdgcn_s_sleep(8);
            if (++spins > 500000) break;   // safety valve: fail loud, not hung
        }
        __builtin_amdgcn_fence(__ATOMIC_ACQUIRE, "agent");
    }
    __syncthreads();
}

__device__ __forceinline__ float edge_w(float as_v, float adn) {
    float e = as_v + adn;
    e = (e > 0.f) ? e : NEG * e;
    return __expf(e);
}

// One wave-group (64 lanes) computes 8 nodes x HD: x staged in the group's own
// LDS slice (wave-synchronous: no __syncthreads needed), W coalesced float2.
template <int K>
__device__ __forceinline__ void gemm8(const float* __restrict__ xin,
                                      const float* __restrict__ W,
                                      const float* __restrict__ atsp,
                                      const float* __restrict__ atdp,
                                      float* __restrict__ h,
                                      float* __restrict__ a_s,
                                      float* __restrict__ a_d,
                                      float* xs, int ng) {
    int t = threadIdx.x;
    int g4 = t >> 6, tt = t & 63, f = tt * 2;
    if (ng < 0 || ng >= NN / 8) return;
    float* xw = xs + g4 * (8 * K);
    {
        float4* xw4 = (float4*)xw;
        const float4* xv = (const float4*)(xin + (size_t)ng * 8 * K);
        #pragma unroll
        for (int i = 0; i < K / 32; i++) xw4[tt + 64 * i] = xv[tt + 64 * i];
    }
    float2 acc[8];
    #pragma unroll
    for (int m = 0; m < 8; m++) acc[m] = make_float2(0.f, 0.f);
    for (int k = 0; k < K; k += 4) {
        float2 w0 = *(const float2*)&W[(k + 0) * HD + f];
        float2 w1 = *(const float2*)&W[(k + 1) * HD + f];
        float2 w2 = *(const float2*)&W[(k + 2) * HD + f];
        float2 w3 = *(const float2*)&W[(k + 3) * HD + f];
        #pragma unroll
        for (int m = 0; m < 8; m++) {
            float4 xk = *(const float4*)&xw[m * K + k];
            acc[m].x += xk.x * w0.x; acc[m].y += xk.x * w0.y;
            acc[m].x += xk.y * w1.x; acc[m].y += xk.y * w1.y;
            acc[m].x += xk.z * w2.x; acc[m].y += xk.z * w2.y;
            acc[m].x += xk.w * w3.x; acc[m].y += xk.w * w3.y;
        }
    }
    float2 ats = *(const float2*)&atsp[f];
    float2 atd = *(const float2*)&atdp[f];
    #pragma unroll
    for (int m = 0; m < 8; m++) {
        int node = ng * 8 + m;
        *(float2*)&h[(size_t)node * HD + f] = acc[m];
        float vs = acc[m].x * ats.x + acc[m].y * ats.y;
        float vd = acc[m].x * atd.x + acc[m].y * atd.y;
        #pragma unroll
        for (int off = 32; off > 0; off >>= 1) {
            vs += __shfl_down(vs, off);
            vd += __shfl_down(vd, off);
        }
        if (tt == 0) { a_s[node] = vs; a_d[node] = vd; }
    }
}

__global__ __launch_bounds__(NT, 4) void k_fused(GatP p) {
    __shared__ float xs[8192];   // 32 KB, reused per phase
    const int t = threadIdx.x;
    const int b = blockIdx.x;
    const int gtid = b * NT + t;

    // ---- P1: histogram of dst (counts pre-zeroed by memset node); seed out=bc ----
    if (gtid == 0) { p.out[0] = p.bc[0]; p.out[1] = p.bc[1]; }
    for (int i = gtid; i < ET; i += GT) {
        int d = (i < EE) ? p.ei[EE + i] : (i - EE);
        atomicAdd(&p.counts[d], 1);
    }
    gbar(p.bar, 1 * NB);

    // ---- P2: block 0 scans counts->offsets/cursor  ||  blocks 1..1023 run gemm1 ----
    if (b == 0) {
        const int CHUNK = 40;   // 256*40 = 10240 >= 10000
        int* sm = (int*)xs;
        int base = t * CHUNK;
        int s = 0;
        for (int i = 0; i < CHUNK; i++) {
            int idx = base + i;
            if (idx < NN) s += p.counts[idx];
        }
        sm[t] = s;
        __syncthreads();
        for (int off = 1; off < NT; off <<= 1) {
            int v = (t >= off) ? sm[t - off] : 0;
            __syncthreads();
            sm[t] += v;
            __syncthreads();
        }
        int run = (t > 0) ? sm[t - 1] : 0;
        for (int i = 0; i < CHUNK; i++) {
            int idx = base + i;
            if (idx < NN) {
                p.offsets[idx] = run;
                p.cursor[idx]  = run;
                run += p.counts[idx];
            }
        }
        if (t == NT - 1) p.offsets[NN] = sm[NT - 1];
    } else {
        // groups 0..1249 over 1023 blocks x wave-groups g4: ng = (b-1) + 1023*g4
        gemm8<FIN>(p.x, p.W1, p.as1, p.ad1, p.h, p.a_s, p.a_d, xs,
                   (b - 1) + 1023 * (t >> 6));
    }
    gbar(p.bar, 2 * NB);

    // ---- P3: scatter source ids into CSR ----
    for (int i = gtid; i < ET; i += GT) {
        int s, d;
        if (i < EE) { s = p.ei[i]; d = p.ei[EE + i]; }
        else        { s = i - EE; d = s; }
        int pos = atomicAdd(&p.cursor[d], 1);
        p.srclist[pos] = s;
    }
    gbar(p.bar, 3 * NB);

    // ---- P4: agg1 (wave per node, 4-deep unroll) -> g1 = relu(agg + b1) ----
    {
        int wv = t >> 6, l = t & 63;
        const float2* h2 = (const float2*)p.h;
        for (int node = (b << 2) + wv; node < NN; node += NB * 4) {
            int beg = p.offsets[node], end = p.offsets[node + 1];
            float adn = p.a_d[node];
            float ax = 0.f, ay = 0.f, z = 0.f;
            int pp = beg;
            for (; pp + 4 <= end; pp += 4) {
                int s0 = p.srclist[pp],     s1 = p.srclist[pp + 1];
                int s2 = p.srclist[pp + 2], s3 = p.srclist[pp + 3];
                float2 h0 = h2[(size_t)s0 * 64 + l];
                float2 h1 = h2[(size_t)s1 * 64 + l];
                float2 hh = h2[(size_t)s2 * 64 + l];
                float2 h3 = h2[(size_t)s3 * 64 + l];
                float w0 = edge_w(p.a_s[s0], adn);
                float w1 = edge_w(p.a_s[s1], adn);
                float w2 = edge_w(p.a_s[s2], adn);
                float w3 = edge_w(p.a_s[s3], adn);
                z += (w0 + w1) + (w2 + w3);
                ax += w0 * h0.x + w1 * h1.x + w2 * hh.x + w3 * h3.x;
                ay += w0 * h0.y + w1 * h1.y + w2 * hh.y + w3 * h3.y;
            }
            for (; pp < end; pp++) {
                int s = p.srclist[pp];
                float2 hv = h2[(size_t)s * 64 + l];
                float ww = edge_w(p.a_s[s], adn);
                z += ww;
                ax += ww * hv.x;
                ay += ww * hv.y;
            }
            float2 bb = *(const float2*)&p.b1[2 * l];
            float ox = ax / z + bb.x, oy = ay / z + bb.y;
            ox = (ox > 0.f) ? ox : 0.f;
            oy = (oy > 0.f) ? oy : 0.f;
            *(float2*)&p.g1[(size_t)node * HD + 2 * l] = make_float2(ox, oy);
        }
    }
    gbar(p.bar, 4 * NB);

    // ---- P5: gemm2  h = g1@W2, a_s, a_d  (ng = b + 1024*g4) ----
    gemm8<HD>(p.g1, p.W2, p.as2, p.ad2, p.h, p.a_s, p.a_d, xs,
              b + NB * (t >> 6));
    gbar(p.bar, 5 * NB);

    // ---- P6: agg2 + reduce_dim + classifier partials -> 2 atomics per block ----
    {
        int wv = t >> 6, l = t & 63;
        const float2* h2 = (const float2*)p.h;
        float br0 = p.br[0];
        float c0 = 0.f, c1 = 0.f;            // lane-0-only classifier partials
        for (int node = (b << 2) + wv; node < NN; node += NB * 4) {
            int beg = p.offsets[node], end = p.offsets[node + 1];
            float adn = p.a_d[node];
            float ax = 0.f, ay = 0.f, z = 0.f;
            int pp = beg;
            for (; pp + 4 <= end; pp += 4) {
                int s0 = p.srclist[pp],     s1 = p.srclist[pp + 1];
                int s2 = p.srclist[pp + 2], s3 = p.srclist[pp + 3];
                float2 h0 = h2[(size_t)s0 * 64 + l];
                float2 h1 = h2[(size_t)s1 * 64 + l];
                float2 hh = h2[(size_t)s2 * 64 + l];
                float2 h3 = h2[(size_t)s3 * 64 + l];
                float w0 = edge_w(p.a_s[s0], adn);
                float w1 = edge_w(p.a_s[s1], adn);
                float w2 = edge_w(p.a_s[s2], adn);
                float w3 = edge_w(p.a_s[s3], adn);
                z += (w0 + w1) + (w2 + w3);
                ax += w0 * h0.x + w1 * h1.x + w2 * hh.x + w3 * h3.x;
                ay += w0 * h0.y + w1 * h1.y + w2 * hh.y + w3 * h3.y;
            }
            for (; pp < end; pp++) {
                int s = p.srclist[pp];
                float2 hv = h2[(size_t)s * 64 + l];
                float ww = edge_w(p.a_s[s], adn);
                z += ww;
                ax += ww * hv.x;
                ay += ww * hv.y;
            }
            float2 bb = *(const float2*)&p.b2[2 * l];
            float ox = ax / z + bb.x, oy = ay / z + bb.y;
            ox = (ox > 0.f) ? ox : 0.f;
            oy = (oy > 0.f) ? oy : 0.f;
            float2 wr = *(const float2*)&p.Wr[2 * l];
            float part = ox * wr.x + oy * wr.y;
            #pragma unroll
            for (int off = 32; off > 0; off >>= 1) part += __shfl_down(part, off);
            if (l == 0) {
                float rv = part + br0;
                c0 += rv * p.Wc[2 * node];
                c1 += rv * p.Wc[2 * node + 1];
            }
        }
        __syncthreads();                      // xs free (P5 reads done in-wave)
        float* cred = xs;
        if (l == 0) { cred[wv] = c0; cred[4 + wv] = c1; }
        __syncthreads();
        if (t == 0) {
            atomicAdd(&p.out[0], cred[0] + cred[1] + cred[2] + cred[3]);
            atomicAdd(&p.out[1], cred[4] + cred[5] + cred[6] + cred[7]);
        }
    }
}

// ---------------- launch: 1 memset node + 1 kernel node ----------------

extern "C" void kernel_launch(void* const* d_in, const int* in_sizes, int n_in,
                              void* d_out, int out_size, void* d_ws, size_t ws_size,
                              hipStream_t stream) {
    GatP p;
    p.x   = (const float*)d_in[0];
    p.ei  = (const int*)d_in[1];
    p.W1  = (const float*)d_in[2];
    p.as1 = (const float*)d_in[3];
    p.ad1 = (const float*)d_in[4];
    p.b1  = (const float*)d_in[5];
    p.W2  = (const float*)d_in[6];
    p.as2 = (const float*)d_in[7];
    p.ad2 = (const float*)d_in[8];
    p.b2  = (const float*)d_in[9];
    p.Wr  = (const float*)d_in[10];
    p.br  = (const float*)d_in[11];
    p.Wc  = (const float*)d_in[12];
    p.bc  = (const float*)d_in[13];
    p.out = (float*)d_out;

    float* f = (float*)d_ws;
    p.h   = f;                      f += (size_t)NN * HD;
    p.g1  = f;                      f += (size_t)NN * HD;
    p.a_s = f;                      f += NN;
    p.a_d = f;                      f += NN;
    int* ip = (int*)f;
    p.counts  = ip;                 ip += NN;      // counts+bar adjacent:
    p.bar     = ip;                 ip += 4;       // one memset covers both
    p.offsets = ip;                 ip += NN + 1;
    p.cursor  = ip;                 ip += NN;
    p.srclist = ip;                 ip += ET;

    hipMemsetAsync(p.counts, 0, (NN + 4) * sizeof(int), stream);
    k_fused<<<NB, NT, 0, stream>>>(p);
}